// Round 4
// baseline (309.334 us; speedup 1.0000x reference)
//
#include <hip/hip_runtime.h>
#include <math.h>

#define Bsz   120
#define Nv    128
#define Ms    192            // checks per s (rows of Hz for s=0, Hx for s=1)
#define Tit   25
#define EMAXS 960            // padded edge slots per s (expected ~768, +7 sigma)

// ws int layout per s: rp[193] | vp[129] | rcol[960] | echk[960] | veid[960]
#define O_RP    0
#define O_VP    193
#define O_RCOL  322
#define O_ECHK  1282
#define O_VEID  2242
#define SSTRIDE 3202
#define WS_PART (2 * SSTRIDE)   // float part[2][Bsz][Tit]

// phi(x) = -log(tanh(x/2)) = ln2*(log2(1+u) - log2(1-u)), u = e^-x, clip [1e-6,30].
// Small-x: 1-u by series to kill cancellation. (Identical to the passing version.)
__device__ __forceinline__ float phi_f(float x) {
  x = fminf(fmaxf(x, 1e-6f), 30.0f);
  const float u = __expf(-x);
  float den = 1.0f - u;
  if (x < 0.03125f) den = x * (1.0f - 0.5f * x + 0.16666667f * x * x);
  return 0.69314718f * (__log2f(1.0f + u) - __log2f(den));
}

// ---------------------------------------------------------------------------
// Setup: ONE block, 384 threads, all-LDS. Row bitmasks -> wave-parallel prefix
// scans -> CSR arrays. No global memory in inner loops, no serial scans.
// ---------------------------------------------------------------------------
__global__ __launch_bounds__(384) void setup_kernel(const float* __restrict__ Hx,
                                                    const float* __restrict__ Hz,
                                                    int* __restrict__ W) {
  __shared__ unsigned mask[2 * Ms][4];   // 128-bit row masks
  __shared__ int rp_s[2][Ms + 1];
  __shared__ int wtot[6];
  __shared__ int vt[4];
  const int tid = threadIdx.x;
  const int lane = tid & 63, wv = tid >> 6;
  const int s = (tid >= Ms) ? 1 : 0;
  const int m = s ? tid - Ms : tid;
  const float* H = s ? Hx : Hz;          // Hs = stack([Hz, Hx])
  int* rpg   = W + s * SSTRIDE + O_RP;
  int* rcolg = W + s * SSTRIDE + O_RCOL;
  int* echkg = W + s * SSTRIDE + O_ECHK;

  // ---- row masks + degree (float4 loads for MLP) ----
  unsigned mw[4];
  int d = 0;
  const float4* H4 = (const float4*)(H + m * Nv);
#pragma unroll
  for (int w = 0; w < 4; ++w) {
    unsigned bits = 0;
#pragma unroll
    for (int q = 0; q < 8; ++q) {
      const float4 v = H4[w * 8 + q];
      if (v.x > 0.f) bits |= 1u << (q * 4 + 0);
      if (v.y > 0.f) bits |= 1u << (q * 4 + 1);
      if (v.z > 0.f) bits |= 1u << (q * 4 + 2);
      if (v.w > 0.f) bits |= 1u << (q * 4 + 3);
    }
    mw[w] = bits;
    mask[tid][w] = bits;
    d += __popc(bits);
  }
  // ---- check-side prefix: shfl scan within wave, carry across waves of same s ----
  int x = d;
#pragma unroll
  for (int off = 1; off < 64; off <<= 1) {
    const int y = __shfl_up(x, off);
    if (lane >= off) x += y;
  }
  if (lane == 63) wtot[wv] = x;
  __syncthreads();
  int carry = 0;
  const int wbase = s ? 3 : 0;
  for (int k = wbase; k < wv; ++k) carry += wtot[k];
  const int incl = x + carry;
  const int excl = incl - d;
  rp_s[s][m] = excl;
  rpg[m] = excl;
  if (m == Ms - 1) { rp_s[s][Ms] = incl; rpg[Ms] = incl; }
  __syncthreads();
  const int Es = rp_s[s][Ms];
  // ---- emit edges (sorted by (row, col): same order as before) ----
  {
    int o = excl;
#pragma unroll
    for (int w = 0; w < 4; ++w) {
      unsigned bits = mw[w];
      while (bits) {
        const int j = __ffs(bits) - 1;
        bits &= bits - 1;
        if (o < EMAXS) { rcolg[o] = w * 32 + j; echkg[o] = m; }
        ++o;
      }
    }
  }
  for (int e = Es + m; e < EMAXS; e += Ms) echkg[e] = Ms;   // dummy check id
  __syncthreads();
  // ---- variable side: tid<256 -> (s2, n); count via column bit, scan, fill ----
  int xv = 0, vcnt = 0;
  if (tid < 2 * Nv) {
    const int s2 = tid >> 7, n = tid & (Nv - 1);
    const int wnd = n >> 5, bit = n & 31;
    int cnt = 0;
    for (int mm = 0; mm < Ms; ++mm)
      cnt += (mask[s2 * Ms + mm][wnd] >> bit) & 1;
    vcnt = cnt;
    xv = cnt;
#pragma unroll
    for (int off = 1; off < 64; off <<= 1) {
      const int y = __shfl_up(xv, off);
      if (lane >= off) xv += y;
    }
    if (lane == 63) vt[wv] = xv;
  }
  __syncthreads();
  if (tid < 2 * Nv) {
    const int s2 = tid >> 7, n = tid & (Nv - 1);
    const int wnd = n >> 5, bit = n & 31;
    int* vpg   = W + s2 * SSTRIDE + O_VP;
    int* veidg = W + s2 * SSTRIDE + O_VEID;
    const int vincl = xv + ((wv == 1) ? vt[0] : (wv == 3) ? vt[2] : 0);
    const int vexcl = vincl - vcnt;
    vpg[n] = vexcl;
    if (n == Nv - 1) vpg[Nv] = vincl;
    int o = vexcl;
    for (int mm = 0; mm < Ms; ++mm) {
      const unsigned wbits = mask[s2 * Ms + mm][wnd];
      if ((wbits >> bit) & 1u) {
        int cb = __popc(wbits & ((1u << bit) - 1u));
        for (int w = 0; w < wnd; ++w) cb += __popc(mask[s2 * Ms + mm][w]);
        veidg[o++] = rp_s[s2][mm] + cb;
      }
    }
  }
}

// ---------------------------------------------------------------------------
// Main: ONE WAVE per (b, s). 192 checks = 3/lane, 128 vars = 2/lane,
// edges in 15 padded 64-slots (uniform guard at Epad). All LDS-resident.
// Barriers are 1-wave s_barriers (cheap). corr + loss fully in registers.
// ---------------------------------------------------------------------------
__global__ __launch_bounds__(64) void nbp_kernel(
    const float* __restrict__ errorx, const float* __restrict__ errorz,
    const float* __restrict__ ep0,
    const float* __restrict__ Gx, const float* __restrict__ Gz,
    const float* __restrict__ w_llr, const float* __restrict__ w_vn,
    const float* __restrict__ w_cn,
    int* __restrict__ W) {
  __shared__ float V[EMAXS];
  __shared__ float p[EMAXS];       // |phi| with V's sign folded (|p| >= 1e-30)
  __shared__ float cnm[EMAXS];
  __shared__ unsigned short echk[EMAXS];
  __shared__ unsigned short veid[EMAXS];
  __shared__ int rp[Ms + 1];
  __shared__ int vp[Nv + 1];
  __shared__ float psum[Ms + 1], tot[Ms + 1];
  __shared__ float ssgn[Ms];
  __shared__ float wls[Tit], wvs[Tit], wcs[Tit];

  const int lane = threadIdx.x;
  const int bid = blockIdx.x;
  const int b = bid >> 1, s = bid & 1;
  const int* base   = W + s * SSTRIDE;
  const int* rp_g   = base + O_RP;
  const int* vp_g   = base + O_VP;
  const int* rcol_g = base + O_RCOL;
  const int* echk_g = base + O_ECHK;
  const int* veid_g = base + O_VEID;
  float* part = (float*)(W + WS_PART) + (s * Bsz + b) * Tit;

  const float ep   = ep0[0];
  const float a23  = (2.0f * ep) / 3.0f;
  const float llr0 = logf((1.0f - a23) / a23);

  // ---- init: CSR ptrs + weights into LDS; G rows + err into registers ----
  for (int i = lane; i <= Ms; i += 64) rp[i] = rp_g[i];
  for (int i = lane; i <= Nv; i += 64) vp[i] = vp_g[i];
  if (lane < Tit) {
    wls[lane] = w_llr[lane];
    wvs[lane] = w_vn[lane];
    wcs[lane] = w_cn[lane];
  }
  const float* G = s ? Gz : Gx;         // s=0: Gx·corrz ; s=1: Gz·corrx
  const float g0a = G[lane], g0b = G[lane + 64];
  const float g1a = G[Nv + lane], g1b = G[Nv + lane + 64];
  const float* ecp = (s ? errorx : errorz) + b * Nv;   // selector for corr
  const float ec0 = ecp[lane], ec1 = ecp[lane + 64];
  __syncthreads();
  const int E = rp[Ms];
  const int Epad = (E + 63) & ~63;

  for (int e = lane; e < EMAXS; e += 64) {
    echk[e] = (unsigned short)echk_g[e];
    veid[e] = (e < E) ? (unsigned short)veid_g[e] : (unsigned short)0;
    V[e] = (e < E) ? llr0 : 1.0f;       // benign pad value
  }
  {
    // s=0: synx = errorx @ Hz.T ; s=1: synz = errorz @ Hx.T
    const float* esyn = (s ? errorz : errorx) + b * Nv;
#pragma unroll
    for (int j = 0; j < 3; ++j) {
      const int c = lane + j * 64;
      int par = 0;
      for (int e = rp[c]; e < rp[c + 1]; ++e)
        par ^= (esyn[rcol_g[e]] > 0.5f) ? 1 : 0;
      ssgn[c] = par ? -1.f : 1.f;
    }
  }
  if (lane == 0) { psum[Ms] = 0.f; tot[Ms] = 0.f; }
  __syncthreads();

  for (int t = 0; t < Tit; ++t) {
    const float wct = wcs[t], wlt = wls[t], wvt = wvs[t];
    // ---- A: edge phi (15 unrolled slots, uniform guard) ----
#pragma unroll
    for (int k = 0; k < 15; ++k) {
      const int e = lane + k * 64;
      if (e < Epad) {
        const float v = V[e];
        float pv = phi_f(fabsf(v));
        pv = fmaxf(pv, 1e-30f);
        p[e] = (v < 0.f) ? -pv : pv;
      }
    }
    __syncthreads();
    // ---- B: per-check psum / signed total (3 checks per lane) ----
#pragma unroll
    for (int j = 0; j < 3; ++j) {
      const int c = lane + j * 64;
      const int beg = rp[c], end = rp[c + 1];
      float sm = 0.f;
      unsigned par = 0;
      for (int e = beg; e < end; ++e) {
        const float ps = p[e];
        par ^= (__float_as_uint(ps) >> 31);
        sm += fabsf(ps);
      }
      psum[c] = sm;
      tot[c] = ((par & 1u) ? -ssgn[c] : ssgn[c]) * wct;
    }
    __syncthreads();
    // ---- C: edge cn messages ----
#pragma unroll
    for (int k = 0; k < 15; ++k) {
      const int e = lane + k * 64;
      if (e < Epad) {
        const int c = echk[e];
        const float ps = p[e];
        const float sg = (__float_as_uint(ps) >> 31) ? -1.f : 1.f;
        cnm[e] = tot[c] * sg * phi_f(psum[c] - fabsf(ps));
      }
    }
    __syncthreads();
    // ---- D: variable update (2 vars per lane), corr in registers ----
    float c0, c1;
    {
      const int beg = vp[lane], end = vp[lane + 1];
      float cs = 0.f;
      for (int k = beg; k < end; ++k) cs += cnm[veid[k]];
      const float bse = wlt * llr0;
      for (int k = beg; k < end; ++k) {
        const int e = veid[k];
        V[e] = bse + wvt * (cs - cnm[e]);
      }
      const float prob = 1.0f / (1.0f + __expf(bse + cs));  // sigmoid(-Gamma)
      c0 = (ec0 > 0.5f) ? 1.0f - prob : prob;
    }
    {
      const int v1 = lane + 64;
      const int beg = vp[v1], end = vp[v1 + 1];
      float cs = 0.f;
      for (int k = beg; k < end; ++k) cs += cnm[veid[k]];
      const float bse = wlt * llr0;
      for (int k = beg; k < end; ++k) {
        const int e = veid[k];
        V[e] = bse + wvt * (cs - cnm[e]);
      }
      const float prob = 1.0f / (1.0f + __expf(bse + cs));
      c1 = (ec1 > 0.5f) ? 1.0f - prob : prob;
    }
    // ---- loss: register dot + butterfly (no barrier needed) ----
    float a = g0a * c0 + g0b * c1;
    float bb = g1a * c0 + g1b * c1;
#pragma unroll
    for (int off = 1; off < 64; off <<= 1) {
      a += __shfl_xor(a, off);
      bb += __shfl_xor(bb, off);
    }
    const float lt = fabsf(__sinf(1.57079632679f * a)) +
                     fabsf(__sinf(1.57079632679f * bb));
    if (lane == 0) part[t] = lt;
    __syncthreads();   // V ready for next iteration's A
  }
}

// ---------------------------------------------------------------------------
// Final combine: loss_t[b] = partA + partB; mean_b(sum_t), mean_b(min_t).
// ---------------------------------------------------------------------------
__global__ __launch_bounds__(128) void reduce_kernel(const int* __restrict__ W,
                                                     float* __restrict__ out) {
  const float* part = (const float*)(W + WS_PART);
  __shared__ float wsum[2], wmin[2];
  const int tid = threadIdx.x;
  float sm = 0.f, mn = 0.f;
  if (tid < Bsz) {
    const float* pa = part + tid * Tit;               // s=0
    const float* pb = part + (Bsz + tid) * Tit;       // s=1
    float acc = 0.f, mloc = 3.0e38f;
    for (int t = 0; t < Tit; ++t) {
      const float lt = pa[t] + pb[t];
      acc += lt;
      mloc = fminf(mloc, lt);
    }
    sm = acc;
    mn = mloc;
  }
  for (int off = 32; off; off >>= 1) {
    sm += __shfl_down(sm, off);
    mn += __shfl_down(mn, off);
  }
  const int w = tid >> 6;
  if ((tid & 63) == 0) { wsum[w] = sm; wmin[w] = mn; }
  __syncthreads();
  if (tid == 0) {
    out[0] = (wsum[0] + wsum[1]) * (1.0f / Bsz);
    out[1] = (wmin[0] + wmin[1]) * (1.0f / Bsz);
  }
}

extern "C" void kernel_launch(void* const* d_in, const int* in_sizes, int n_in,
                              void* d_out, int out_size, void* d_ws, size_t ws_size,
                              hipStream_t stream) {
  const float* errorx = (const float*)d_in[0];
  const float* errorz = (const float*)d_in[1];
  const float* ep0    = (const float*)d_in[2];
  const float* Hx     = (const float*)d_in[3];
  const float* Hz     = (const float*)d_in[4];
  const float* Gx     = (const float*)d_in[5];
  const float* Gz     = (const float*)d_in[6];
  const float* wllr   = (const float*)d_in[7];
  const float* wvn    = (const float*)d_in[8];
  const float* wcn    = (const float*)d_in[9];
  float* out = (float*)d_out;
  int* W = (int*)d_ws;

  hipLaunchKernelGGL(setup_kernel, dim3(1), dim3(384), 0, stream, Hx, Hz, W);
  hipLaunchKernelGGL(nbp_kernel, dim3(2 * Bsz), dim3(64), 0, stream,
                     errorx, errorz, ep0, Gx, Gz, wllr, wvn, wcn, W);
  hipLaunchKernelGGL(reduce_kernel, dim3(1), dim3(128), 0, stream, W, out);
}

// Round 5
// 269.442 us; speedup vs baseline: 1.1481x; 1.1481x over previous
//
#include <hip/hip_runtime.h>
#include <math.h>

#define Bsz 120
#define Nv  128
#define Ms  192            // checks per s (rows of Hz for s=0, Hx for s=1)
#define Tit 25
#define DC  16             // max check degree (padded slots)
#define DV  24             // max var degree (padded slots)

// ws int layout per s (rank-indexed, degree-sorted):
//  cdeg[192] | ncol[192*16 ushort] | vdeg[128] | vid[128] | veid[128*24 ushort]
#define O_CDEG 0
#define O_NCOL 192
#define O_VDEG 1728
#define O_VID  1856
#define O_VEID 1984
#define SSTRIDE 3520
#define WS_PART (2 * SSTRIDE)   // float part[2][Bsz][Tit]

// phi(x) = -log(tanh(x/2)) = ln2*(log2(1+u) - log2(1-u)), u = e^-x, clip [1e-6,30].
// Small-x: 1-u by series to kill cancellation. (Bit-identical to passing version.)
__device__ __forceinline__ float phi_f(float x) {
  x = fminf(fmaxf(x, 1e-6f), 30.0f);
  const float u = __expf(-x);
  float den = 1.0f - u;
  if (x < 0.03125f) den = x * (1.0f - 0.5f * x + 0.16666667f * x * x);
  return 0.69314718f * (__log2f(1.0f + u) - __log2f(den));
}

// ---------------------------------------------------------------------------
// Setup: ONE block, 384 threads. Row bitmasks -> degree-sorted rank for checks
// (3 slots x 64 lanes) and vars (2 slots x 64 lanes) -> positional tables.
// Edge slot id = ((slot*DC + k)*64 + lane), k = within-check rank (n ascending).
// ---------------------------------------------------------------------------
__global__ __launch_bounds__(384) void setup_kernel(const float* __restrict__ Hx,
                                                    const float* __restrict__ Hz,
                                                    int* __restrict__ W) {
  __shared__ unsigned mask[2 * Ms][4];
  __shared__ int degs[2 * Ms];
  __shared__ int pos[2 * Ms];     // rank of check m within its s
  __shared__ int vdegs[2 * Nv];
  const int tid = threadIdx.x;
  const int s = (tid >= Ms) ? 1 : 0;
  const int m = s ? tid - Ms : tid;
  const float* H = s ? Hx : Hz;   // Hs = stack([Hz, Hx])

  // row masks + degree
  unsigned mw[4];
  int d = 0;
  const float4* H4 = (const float4*)(H + m * Nv);
#pragma unroll
  for (int w = 0; w < 4; ++w) {
    unsigned bits = 0;
#pragma unroll
    for (int q = 0; q < 8; ++q) {
      const float4 v = H4[w * 8 + q];
      if (v.x > 0.f) bits |= 1u << (q * 4 + 0);
      if (v.y > 0.f) bits |= 1u << (q * 4 + 1);
      if (v.z > 0.f) bits |= 1u << (q * 4 + 2);
      if (v.w > 0.f) bits |= 1u << (q * 4 + 3);
    }
    mw[w] = bits;
    mask[tid][w] = bits;
    d += __popc(bits);
  }
  degs[tid] = d;
  __syncthreads();
  // degree-descending rank within s (deterministic tiebreak by m)
  {
    const int base = s * Ms;
    int r = 0;
    for (int m2 = 0; m2 < Ms; ++m2) {
      const int d2 = degs[base + m2];
      r += (d2 > d) || (d2 == d && m2 < m);
    }
    pos[tid] = r;
    int* cdeg_g = W + s * SSTRIDE + O_CDEG;
    cdeg_g[r] = (d <= DC) ? d : DC;
    unsigned short* ncol_g = (unsigned short*)(W + s * SSTRIDE + O_NCOL);
    int k = 0;
#pragma unroll
    for (int w = 0; w < 4; ++w) {
      unsigned bits = mw[w];
      while (bits) {
        const int j = __ffs(bits) - 1;
        bits &= bits - 1;
        if (k < DC) ncol_g[r * DC + k] = (unsigned short)(w * 32 + j);
        ++k;
      }
    }
    for (int kk = (k < DC ? k : DC); kk < DC; ++kk) ncol_g[r * DC + kk] = 0;
  }
  __syncthreads();
  // variable side
  if (tid < 2 * Nv) {
    const int s2 = tid >> 7, n = tid & (Nv - 1);
    const int wnd = n >> 5, bit = n & 31;
    int vd = 0;
    for (int m2 = 0; m2 < Ms; ++m2)
      vd += (mask[s2 * Ms + m2][wnd] >> bit) & 1;
    vdegs[tid] = vd;
  }
  __syncthreads();
  if (tid < 2 * Nv) {
    const int s2 = tid >> 7, n = tid & (Nv - 1);
    const int wnd = n >> 5, bit = n & 31;
    const int vd = vdegs[tid];
    const int base = s2 * Nv;
    int rv = 0;
    for (int n2 = 0; n2 < Nv; ++n2) {
      const int v2 = vdegs[base + n2];
      rv += (v2 > vd) || (v2 == vd && n2 < n);
    }
    int* vid_g = W + s2 * SSTRIDE + O_VID;
    vid_g[rv] = n;
    unsigned short* veid_g = (unsigned short*)(W + s2 * SSTRIDE + O_VEID);
    int kk = 0;
    for (int m2 = 0; m2 < Ms; ++m2) {
      const unsigned wb = mask[s2 * Ms + m2][wnd];
      if ((wb >> bit) & 1u) {
        int ke = __popc(wb & ((1u << bit) - 1u));
        for (int w = 0; w < wnd; ++w) ke += __popc(mask[s2 * Ms + m2][w]);
        if (ke < DC) {
          const int rc = pos[s2 * Ms + m2];
          const int slot = rc >> 6, ln = rc & 63;
          if (kk < DV)
            veid_g[rv * DV + kk] = (unsigned short)(((slot * DC + ke) << 6) | ln);
          ++kk;
        }
      }
    }
    int* vdeg_g = W + s2 * SSTRIDE + O_VDEG;
    vdeg_g[rv] = (kk <= DV) ? kk : DV;
    for (int z = (kk < DV ? kk : DV); z < DV; ++z) veid_g[rv * DV + z] = 0;
  }
}

// ---------------------------------------------------------------------------
// Main: ONE WAVE per (b, s). Whole graph in registers: 3 checks/lane
// (deg, cols, persistent cn messages), 2 vars/lane (edge-slot ids).
// Per iter: P1 check-local (csum gather + phi x2 + cnm stores, all unrolled)
//           P2 var-local (cnm gather + csum store + corr + loss butterfly).
// 2 single-wave barriers per iteration; V reconstructed, never stored.
// ---------------------------------------------------------------------------
__global__ __launch_bounds__(64) void nbp_kernel(
    const float* __restrict__ errorx, const float* __restrict__ errorz,
    const float* __restrict__ ep0,
    const float* __restrict__ Gx, const float* __restrict__ Gz,
    const float* __restrict__ w_llr, const float* __restrict__ w_vn,
    const float* __restrict__ w_cn,
    int* __restrict__ W) {
  __shared__ float cnm[3 * DC * 64];     // [(slot*DC + k)*64 + lane]
  __shared__ float csum[Nv];
  __shared__ float esyn_s[Nv];
  __shared__ float wls[Tit], wvs[Tit], wcs[Tit];

  const int lane = threadIdx.x;
  const int bid = blockIdx.x;
  const int b = bid >> 1, s = bid & 1;
  const int* base = W + s * SSTRIDE;
  const int* cdeg_g = base + O_CDEG;
  const unsigned short* ncol_g = (const unsigned short*)(base + O_NCOL);
  const int* vdeg_g = base + O_VDEG;
  const int* vid_g  = base + O_VID;
  const unsigned short* veid_g = (const unsigned short*)(base + O_VEID);
  float* part = (float*)(W + WS_PART) + (s * Bsz + b) * Tit;

  const float ep   = ep0[0];
  const float a23  = (2.0f * ep) / 3.0f;
  const float llr0 = logf((1.0f - a23) / a23);

  if (lane < Tit) {
    wls[lane] = w_llr[lane];
    wvs[lane] = w_vn[lane];
    wcs[lane] = w_cn[lane];
  }
  {
    const float* esyn = (s ? errorz : errorx) + b * Nv;  // syndrome selector
    esyn_s[lane] = esyn[lane];
    esyn_s[lane + 64] = esyn[lane + 64];
  }
  csum[lane] = 0.f;
  csum[lane + 64] = 0.f;

  // ---- check-side registers ----
  int deg[3];
  unsigned ncp[3][8];                    // 16 packed ushort cols per check
#pragma unroll
  for (int j = 0; j < 3; ++j) {
    const int r = lane + 64 * j;
    deg[j] = cdeg_g[r];
    const uint4* q = (const uint4*)(ncol_g + r * DC);
    const uint4 a0 = q[0], a1 = q[1];
    ncp[j][0] = a0.x; ncp[j][1] = a0.y; ncp[j][2] = a0.z; ncp[j][3] = a0.w;
    ncp[j][4] = a1.x; ncp[j][5] = a1.y; ncp[j][6] = a1.z; ncp[j][7] = a1.w;
  }
  // ---- var-side registers ----
  int vd[2], vidn[2];
  unsigned vep[2][12];                   // 24 packed ushort edge-slot ids
#pragma unroll
  for (int jv = 0; jv < 2; ++jv) {
    const int rv = lane + 64 * jv;
    vd[jv] = vdeg_g[rv];
    vidn[jv] = vid_g[rv];
    const uint4* q = (const uint4*)(veid_g + rv * DV);
    const uint4 a0 = q[0], a1 = q[1], a2 = q[2];
    vep[jv][0] = a0.x; vep[jv][1] = a0.y; vep[jv][2]  = a0.z; vep[jv][3]  = a0.w;
    vep[jv][4] = a1.x; vep[jv][5] = a1.y; vep[jv][6]  = a1.z; vep[jv][7]  = a1.w;
    vep[jv][8] = a2.x; vep[jv][9] = a2.y; vep[jv][10] = a2.z; vep[jv][11] = a2.w;
  }
  const float* G = s ? Gz : Gx;          // s=0: Gx·corrz ; s=1: Gz·corrx
  const float* ecp = (s ? errorx : errorz) + b * Nv;   // corr selector
  float ga[2], gb[2], ec[2];
#pragma unroll
  for (int jv = 0; jv < 2; ++jv) {
    ga[jv] = G[vidn[jv]];
    gb[jv] = G[Nv + vidn[jv]];
    ec[jv] = ecp[vidn[jv]];
  }
  __syncthreads();

  // ---- syndrome signs (registers) ----
  float ssgn[3];
#pragma unroll
  for (int j = 0; j < 3; ++j) {
    int par = 0;
#pragma unroll
    for (int k = 0; k < DC; ++k)
      if (k < deg[j]) {
        const int n = (ncp[j][k >> 1] >> ((k & 1) * 16)) & 0xffff;
        par ^= (esyn_s[n] > 0.5f) ? 1 : 0;
      }
    ssgn[j] = par ? -1.f : 1.f;
  }

  float cn_r[3][DC];
#pragma unroll
  for (int j = 0; j < 3; ++j)
#pragma unroll
    for (int k = 0; k < DC; ++k) cn_r[j][k] = 0.f;

  float basePrev = llr0, wvPrev = 0.f;   // makes t=0 reconstruct V = llr0 exactly

#pragma unroll 1
  for (int t = 0; t < Tit; ++t) {
    const float wct = wcs[t];
    // ---- P1: check-local ----
#pragma unroll
    for (int j = 0; j < 3; ++j) {
      float pa[DC];
      float psum = 0.f;
      unsigned par = 0;
#pragma unroll
      for (int k = 0; k < DC; ++k)
        if (k < deg[j]) {
          const int n = (ncp[j][k >> 1] >> ((k & 1) * 16)) & 0xffff;
          const float Vk = basePrev + wvPrev * (csum[n] - cn_r[j][k]);
          float pv = phi_f(fabsf(Vk));
          pv = fmaxf(pv, 1e-30f);
          par ^= __float_as_uint(Vk) >> 31;
          pa[k] = (Vk < 0.f) ? -pv : pv;
          psum += pv;
        }
      const float totj = ((par & 1u) ? -ssgn[j] : ssgn[j]) * wct;
#pragma unroll
      for (int k = 0; k < DC; ++k)
        if (k < deg[j]) {
          const float ps = pa[k];
          const float sg = (__float_as_uint(ps) >> 31) ? -1.f : 1.f;
          const float cnk = totj * sg * phi_f(psum - fabsf(ps));
          cn_r[j][k] = cnk;
          cnm[((j * DC + k) << 6) + lane] = cnk;
        }
    }
    __syncthreads();
    // ---- P2: var-local + loss ----
    const float wlt = wls[t];
    const float base_t = wlt * llr0;
    float cv[2];
#pragma unroll
    for (int jv = 0; jv < 2; ++jv) {
      float cs = 0.f;
#pragma unroll
      for (int k = 0; k < DV; ++k)
        if (k < vd[jv]) {
          const int e = (vep[jv][k >> 1] >> ((k & 1) * 16)) & 0xffff;
          cs += cnm[e];
        }
      csum[vidn[jv]] = cs;
      const float prob = 1.0f / (1.0f + __expf(base_t + cs));  // sigmoid(-Gamma)
      cv[jv] = (ec[jv] > 0.5f) ? 1.0f - prob : prob;
    }
    float a = ga[0] * cv[0] + ga[1] * cv[1];
    float b2 = gb[0] * cv[0] + gb[1] * cv[1];
#pragma unroll
    for (int off = 1; off < 64; off <<= 1) {
      a += __shfl_xor(a, off);
      b2 += __shfl_xor(b2, off);
    }
    const float lt = fabsf(__sinf(1.57079632679f * a)) +
                     fabsf(__sinf(1.57079632679f * b2));
    if (lane == 0) part[t] = lt;
    basePrev = base_t;
    wvPrev = wvs[t];
    __syncthreads();
  }
}

// ---------------------------------------------------------------------------
// Final combine: loss_t[b] = partA + partB; mean_b(sum_t), mean_b(min_t).
// ---------------------------------------------------------------------------
__global__ __launch_bounds__(128) void reduce_kernel(const int* __restrict__ W,
                                                     float* __restrict__ out) {
  const float* part = (const float*)(W + WS_PART);
  __shared__ float wsum[2], wmin[2];
  const int tid = threadIdx.x;
  float sm = 0.f, mn = 0.f;
  if (tid < Bsz) {
    const float* pa = part + tid * Tit;               // s=0
    const float* pb = part + (Bsz + tid) * Tit;       // s=1
    float acc = 0.f, mloc = 3.0e38f;
    for (int t = 0; t < Tit; ++t) {
      const float lt = pa[t] + pb[t];
      acc += lt;
      mloc = fminf(mloc, lt);
    }
    sm = acc;
    mn = mloc;
  }
  for (int off = 32; off; off >>= 1) {
    sm += __shfl_down(sm, off);
    mn += __shfl_down(mn, off);
  }
  const int w = tid >> 6;
  if ((tid & 63) == 0) { wsum[w] = sm; wmin[w] = mn; }
  __syncthreads();
  if (tid == 0) {
    out[0] = (wsum[0] + wsum[1]) * (1.0f / Bsz);
    out[1] = (wmin[0] + wmin[1]) * (1.0f / Bsz);
  }
}

extern "C" void kernel_launch(void* const* d_in, const int* in_sizes, int n_in,
                              void* d_out, int out_size, void* d_ws, size_t ws_size,
                              hipStream_t stream) {
  const float* errorx = (const float*)d_in[0];
  const float* errorz = (const float*)d_in[1];
  const float* ep0    = (const float*)d_in[2];
  const float* Hx     = (const float*)d_in[3];
  const float* Hz     = (const float*)d_in[4];
  const float* Gx     = (const float*)d_in[5];
  const float* Gz     = (const float*)d_in[6];
  const float* wllr   = (const float*)d_in[7];
  const float* wvn    = (const float*)d_in[8];
  const float* wcn    = (const float*)d_in[9];
  float* out = (float*)d_out;
  int* W = (int*)d_ws;

  hipLaunchKernelGGL(setup_kernel, dim3(1), dim3(2 * Ms), 0, stream, Hx, Hz, W);
  hipLaunchKernelGGL(nbp_kernel, dim3(2 * Bsz), dim3(64), 0, stream,
                     errorx, errorz, ep0, Gx, Gz, wllr, wvn, wcn, W);
  hipLaunchKernelGGL(reduce_kernel, dim3(1), dim3(128), 0, stream, W, out);
}